// Round 2
// baseline (78.513 us; speedup 1.0000x reference)
//
#include <hip/hip_runtime.h>
#include <cmath>

#define SITE 8
#define DIM 16
#define BATCH 8192
#define NPAT 256

// Kernel 1: build the 28 distinct site matrices ONCE per block (they are
// pattern-independent: 7 sites x 2 bits x 2 output-parities), then run
// 8 patterns per block through the 7-step recurrence in LDS.
// grid = 32 blocks x 256 threads; block b handles patterns b*8 .. b*8+7.
__global__ __launch_bounds__(256) void pattern_kernel(
    const float* __restrict__ embedding,  // (8,2,16)
    const float* __restrict__ head_w,     // (32,32)
    const float* __restrict__ body_w,     // (7,32,32,32)
    float* __restrict__ pat)              // (256,32): [e(16), o(16)]
{
    __shared__ float M[7][2][2][256];     // [site-1][bit][h][k*16+j]
    __shared__ float hv[2][16];           // head vectors: [0]=e(bit0), [1]=o(bit1)
    __shared__ float st[8][2][16];        // per-pattern state

    const int tid = threadIdx.x;
    const int pbase = blockIdx.x * 8;

    // ---- Build 28 matrices: entry idx = ((s*2+bit)*2+h)*256 + k*16 + j ----
    // thread t handles (k,j) = (t>>4, t&15) of matrix r for r = 0..27
    {
        const int k = tid >> 4;
        const int j = tid & 15;
        for (int r = 0; r < 28; ++r) {
            int s   = r >> 2;
            int bit = (r >> 1) & 1;
            int h   = r & 1;
            const float* g3  = body_w + s * 32768;
            const float* emb = embedding + (s + 1) * 32 + bit * 16;
            float acc = 0.f;
            if (bit == 0) {
                if (h == 0) {      // +sum_i emb0[i]*g3[k][i][j]          (LLL)
                    #pragma unroll
                    for (int i = 0; i < 16; ++i) acc += emb[i] * g3[k*1024 + i*32 + j];
                } else {           // +sum_i emb0[i]*g3[k+16][i][j+16]    (HLH)
                    #pragma unroll
                    for (int i = 0; i < 16; ++i) acc += emb[i] * g3[(k+16)*1024 + i*32 + (j+16)];
                }
            } else {
                if (h == 0) {      // -sum_i emb1[i]*g3[k+16][i+16][j]    (HHL)
                    #pragma unroll
                    for (int i = 0; i < 16; ++i) acc -= emb[i] * g3[(k+16)*1024 + (i+16)*32 + j];
                } else {           // +sum_i emb1[i]*g3[k][i+16][j+16]    (LHH)
                    #pragma unroll
                    for (int i = 0; i < 16; ++i) acc += emb[i] * g3[k*1024 + (i+16)*32 + (j+16)];
                }
            }
            M[s][bit][h][tid & 255] = acc;  // (k*16+j) == tid since 256 threads
        }
    }

    // ---- Head vectors (threads 0..31): hv[0]=tanh(emb00 . LL), hv[1]=tanh(emb01 . HH)
    if (tid < 32) {
        int h = tid >> 4;
        int j = tid & 15;
        const float* emb = embedding + h * 16;   // site 0, row h
        float a = 0.f;
        if (h == 0) {
            #pragma unroll
            for (int k = 0; k < 16; ++k) a += emb[k] * head_w[k*32 + j];
        } else {
            #pragma unroll
            for (int k = 0; k < 16; ++k) a += emb[k] * head_w[(k+16)*32 + (j+16)];
        }
        hv[h][j] = tanhf(a);
    }
    __syncthreads();

    // ---- Init per-pattern state: bit0=0 -> e=hv0,o=0 ; bit0=1 -> e=0,o=hv1
    {
        int pl = tid >> 5;          // pattern-local 0..7
        int h  = (tid >> 4) & 1;
        int j  = tid & 15;
        int bit0 = (pbase + pl) & 1;
        st[pl][h][j] = (h == bit0) ? hv[h][j] : 0.f;
    }
    __syncthreads();

    // ---- 7-step recurrence ----
    for (int s = 1; s < SITE; ++s) {
        int pl = tid >> 5;
        int h  = (tid >> 4) & 1;
        int j  = tid & 15;
        int bit = ((pbase + pl) >> s) & 1;
        const float* src = st[pl][h ^ bit];     // input-swap on bit=1
        const float* m   = &M[s-1][bit][h][0];
        float a = 0.f;
        #pragma unroll
        for (int k = 0; k < 16; ++k) a += src[k] * m[k*16 + j];
        float nv = tanhf(a);
        __syncthreads();
        st[pl][h][j] = nv;
        __syncthreads();
    }

    // ---- Emit pattern table ----
    {
        int pl = tid >> 5;
        int h  = (tid >> 4) & 1;
        int j  = tid & 15;
        pat[(pbase + pl) * 32 + h * 16 + j] = st[pl][h][j];
    }
}

// Kernel 2: scatter, one thread per output float4.
// out row b (64 floats = 16 float4): q<4 -> e, q>=12 -> o, else 0.
__global__ __launch_bounds__(256) void scatter_kernel(
    const int* __restrict__ data,     // (8192,8)
    const float4* __restrict__ pat4,  // (256,8) float4
    float4* __restrict__ out4)        // (8192,16) float4
{
    int gid = blockIdx.x * 256 + threadIdx.x;   // 0 .. 131071
    int b = gid >> 4;
    int q = gid & 15;
    const int4* d4 = (const int4*)(data + b * 8);
    int4 w0 = d4[0];
    int4 w1 = d4[1];
    int id = (w0.x & 1) | ((w0.y & 1) << 1) | ((w0.z & 1) << 2) | ((w0.w & 1) << 3)
           | ((w1.x & 1) << 4) | ((w1.y & 1) << 5) | ((w1.z & 1) << 6) | ((w1.w & 1) << 7);
    float4 v = make_float4(0.f, 0.f, 0.f, 0.f);
    if (q < 4)       v = pat4[id * 8 + q];
    else if (q >= 12) v = pat4[id * 8 + (q - 8)];
    out4[b * 16 + q] = v;
}

extern "C" void kernel_launch(void* const* d_in, const int* in_sizes, int n_in,
                              void* d_out, int out_size, void* d_ws, size_t ws_size,
                              hipStream_t stream) {
    const int*   data      = (const int*)d_in[0];
    const float* embedding = (const float*)d_in[1];
    const float* head_w    = (const float*)d_in[2];
    const float* body_w    = (const float*)d_in[3];
    float* pat = (float*)d_ws;   // 256*32 floats = 32 KB

    pattern_kernel<<<32, 256, 0, stream>>>(embedding, head_w, body_w, pat);
    scatter_kernel<<<(BATCH * 16) / 256, 256, 0, stream>>>(data, (const float4*)pat,
                                                           (float4*)d_out);
}